// Round 20
// baseline (1274.275 us; speedup 1.0000x reference)
//
#include <hip/hip_runtime.h>
#include <hip/hip_bf16.h>

#define NEG_SLOPE 0.2f
#define BCAP 1536u   // fixed ebuf capacity per 64-node bucket (mean 1024, +16 sigma)

typedef __attribute__((ext_vector_type(8))) short bf16x8;
typedef __attribute__((ext_vector_type(4))) float f32x4;

__device__ __forceinline__ float lrelu(float v) { return v > 0.0f ? v : NEG_SLOPE * v; }

__device__ __forceinline__ unsigned bf16pair(float a, float b) {
    unsigned ua = __float_as_uint(a), ub = __float_as_uint(b);
    ua = (ua + 0x7FFFu + ((ua >> 16) & 1u)) >> 16;
    ub = (ub + 0x7FFFu + ((ub >> 16) & 1u)) >> 16;
    return ua | (ub << 16);
}

__device__ __forceinline__ void gload16(const void* g, void* l) {
    __builtin_amdgcn_global_load_lds(
        (const __attribute__((address_space(1))) unsigned*)g,
        (__attribute__((address_space(3))) unsigned*)l, 16, 0, 0);
}

// ---------------- Wt: W fp32 [k][n] -> Wt bf16 [n][k] ----------------
__global__ __launch_bounds__(256) void k_wt(const float* __restrict__ W,
                                            unsigned short* __restrict__ Wt) {
    int gid = blockIdx.x * 256 + threadIdx.x;
    int col = gid >> 7, k = gid & 127;
    float v = W[(size_t)k * 128 + col];
    unsigned u = __float_as_uint(v);
    u = (u + 0x7FFFu + ((u >> 16) & 1u)) >> 16;
    Wt[col * 128 + k] = (unsigned short)u;
}

// ---------------- fused: bucket blocks (first NBK) + gemm blocks ------------
__global__ __launch_bounds__(512) void k_gembk(const float* __restrict__ x,
                                               const unsigned short* __restrict__ Wt,
                                               const float* __restrict__ att_src,
                                               const float* __restrict__ att_dst,
                                               unsigned* __restrict__ hb,
                                               float* __restrict__ a_src,
                                               float* __restrict__ a_dst,
                                               const int* __restrict__ ei,
                                               unsigned* __restrict__ gcur,
                                               unsigned* __restrict__ ebuf,
                                               int N, int E, int NB2, int NBK, int EPB) {
    __shared__ unsigned char sm[65536];
    int t = threadIdx.x;

    if ((int)blockIdx.x < NBK) {
        // ---- bucket path: fixed regions, 4B entries src|(d&63)<<24 ----
        unsigned* cnt = (unsigned*)sm;            // 2048 entries
        unsigned* cur2 = (unsigned*)(sm + 8192);
        unsigned* lbase = (unsigned*)(sm + 16384);
        int base = blockIdx.x * EPB;
        int lim = base + EPB;
        if (lim > E) lim = E;
        for (int j = t; j < NB2; j += 512) { cnt[j] = 0u; cur2[j] = 0u; }
        __syncthreads();
        for (int i = base + t; i < lim; i += 512)
            atomicAdd(&cnt[(unsigned)ei[(size_t)E + i] >> 6], 1u);
        __syncthreads();
        for (int j = t; j < NB2; j += 512) {
            unsigned c = cnt[j];
            lbase[j] = c ? ((unsigned)j * BCAP + atomicAdd(&gcur[j], c)) : 0u;
        }
        __syncthreads();
        for (int i = base + t; i < lim; i += 512) {
            unsigned s = (unsigned)ei[i];
            unsigned d = (unsigned)ei[(size_t)E + i];
            unsigned b = d >> 6;
            unsigned k = atomicAdd(&cur2[b], 1u);
            unsigned slot = lbase[b] + k;
            if (slot < (b + 1u) * BCAP) ebuf[slot] = s | ((d & 63u) << 24);
        }
        return;
    }

    // ---------------- gemm path ----------------
    unsigned char* smA = sm;
    unsigned char* smB = sm + 32768;
    int w = t >> 6, lane = t & 63;
    int row0 = ((int)blockIdx.x - NBK) * 128;

#pragma unroll
    for (int it = 0; it < 4; ++it) {
        int L = it * 512 + t;
        int r = L >> 4, c = L & 15;
        int gr = row0 + r;
        if (gr >= N) gr = N - 1;
        float4 f0 = ((const float4*)x)[(size_t)gr * 32 + c * 2];
        float4 f1 = ((const float4*)x)[(size_t)gr * 32 + c * 2 + 1];
        uint4 u;
        u.x = bf16pair(f0.x, f0.y);
        u.y = bf16pair(f0.z, f0.w);
        u.z = bf16pair(f1.x, f1.y);
        u.w = bf16pair(f1.z, f1.w);
        *(uint4*)&smA[r * 256 + ((c ^ (r & 7)) * 16)] = u;
    }
#pragma unroll
    for (int it = 0; it < 4; ++it) {
        int L = w * 256 + it * 64 + lane;
        int r = L >> 4, c = L & 15;
        int cg = c ^ (r & 7);
        gload16((const unsigned*)Wt + r * 64 + cg * 4, smB + (size_t)w * 4096 + it * 1024);
    }
    __syncthreads();

    int lr = lane & 15, lg = lane >> 4;
    int ar = w * 16 + lr;

    f32x4 acc[8];
#pragma unroll
    for (int j = 0; j < 8; ++j)
#pragma unroll
        for (int q = 0; q < 4; ++q) acc[j][q] = 0.f;

#pragma unroll
    for (int kc = 0; kc < 4; ++kc) {
        bf16x8 av = *(const bf16x8*)&smA[ar * 256 + (((kc * 4 + lg) ^ (ar & 7)) * 16)];
        bf16x8 bv[8];
#pragma unroll
        for (int cf = 0; cf < 8; ++cf) {
            int bc = cf * 16 + lr;
            bv[cf] = *(const bf16x8*)&smB[bc * 256 + (((kc * 4 + lg) ^ (bc & 7)) * 16)];
        }
#pragma unroll
        for (int cf = 0; cf < 8; ++cf)
            acc[cf] = __builtin_amdgcn_mfma_f32_16x16x32_bf16(av, bv[cf], acc[cf], 0, 0, 0);
    }

    float att_s[8], att_d[8];
#pragma unroll
    for (int cf = 0; cf < 8; ++cf) {
        att_s[cf] = att_src[cf * 16 + lr];
        att_d[cf] = att_dst[cf * 16 + lr];
    }
#pragma unroll
    for (int reg = 0; reg < 4; ++reg) {
        int row = row0 + w * 16 + lg * 4 + reg;
        float ps[4], pd[4];
#pragma unroll
        for (int hh = 0; hh < 4; ++hh) {
            ps[hh] = acc[2 * hh][reg] * att_s[2 * hh] + acc[2 * hh + 1][reg] * att_s[2 * hh + 1];
            pd[hh] = acc[2 * hh][reg] * att_d[2 * hh] + acc[2 * hh + 1][reg] * att_d[2 * hh + 1];
        }
#pragma unroll
        for (int m = 1; m <= 8; m <<= 1) {
#pragma unroll
            for (int hh = 0; hh < 4; ++hh) {
                ps[hh] += __shfl_xor(ps[hh], m);
                pd[hh] += __shfl_xor(pd[hh], m);
            }
        }
        if (lr == 0 && row < N) {
            ((float4*)a_src)[row] = float4{ps[0], ps[1], ps[2], ps[3]};
            ((float4*)a_dst)[row] = float4{pd[0], pd[1], pd[2], pd[3]};
        }
    }

    unsigned char* scratch = smA + (size_t)w * 4096;
#pragma unroll
    for (int cf = 0; cf < 8; ++cf) {
#pragma unroll
        for (int reg = 0; reg < 4; ++reg) {
            float v = acc[cf][reg];
            float vo = __shfl_xor(v, 1);
            if (!(lane & 1))
                *(unsigned*)&scratch[(lg * 4 + reg) * 256 + cf * 32 + (lr >> 1) * 4] =
                    bf16pair(v, vo);
        }
    }
#pragma unroll
    for (int q = 0; q < 4; ++q) {
        uint4 u = *(const uint4*)&scratch[q * 1024 + lane * 16];
        int row = row0 + w * 16 + q * 4 + lg;
        if (row < N) ((uint4*)hb)[(size_t)row * 16 + lr] = u;
    }
}

// --------- bucket-gather: LDS fp32 accumulators, one block per 64 nodes ------
__global__ __launch_bounds__(512) void k_bg(const uint4* __restrict__ hb4,
                                            const unsigned* __restrict__ ebuf,
                                            const unsigned* __restrict__ gcur,
                                            const float* __restrict__ a_src,
                                            const float* __restrict__ a_dst,
                                            const float* __restrict__ bias,
                                            float* __restrict__ out, int N) {
    __shared__ float acc[64 * 132];   // [node][132] (pad 4 vs bank conflicts)
    __shared__ float accd[64 * 4];    // per-node per-head denominator
    int t = threadIdx.x;
    int b = blockIdx.x;
    for (int i = t; i < 64 * 132; i += 512) acc[i] = 0.f;
    if (t < 256) accd[t] = 0.f;
    __syncthreads();

    unsigned cnt = gcur[b];
    if (cnt > BCAP) cnt = BCAP;
    unsigned ebase = (unsigned)b * BCAP;
    int nodeBase = b * 64;

    int gid = t >> 4;      // 32 edge-groups of 16 lanes
    int L = t & 15;        // channel block 8L..8L+7
    int head = L >> 2;
    for (unsigned i = gid; i < cnt; i += 32) {
        unsigned e = ebuf[ebase + i];
        unsigned s = e & 0x00FFFFFFu;
        unsigned dLow = e >> 24;
        float p = __expf(lrelu(a_src[s * 4 + head] + a_dst[(nodeBase + dLow) * 4 + head]));
        uint4 u = hb4[s * 16u + (unsigned)L];
        float* ar = &acc[dLow * 132 + L * 8];
        atomicAdd(&ar[0], p * __uint_as_float(u.x << 16));
        atomicAdd(&ar[1], p * __uint_as_float(u.x & 0xFFFF0000u));
        atomicAdd(&ar[2], p * __uint_as_float(u.y << 16));
        atomicAdd(&ar[3], p * __uint_as_float(u.y & 0xFFFF0000u));
        atomicAdd(&ar[4], p * __uint_as_float(u.z << 16));
        atomicAdd(&ar[5], p * __uint_as_float(u.z & 0xFFFF0000u));
        atomicAdd(&ar[6], p * __uint_as_float(u.w << 16));
        atomicAdd(&ar[7], p * __uint_as_float(u.w & 0xFFFF0000u));
        if ((L & 3) == 0) atomicAdd(&accd[dLow * 4 + head], p);
    }
    __syncthreads();

    // epilogue: 8 waves; wave w handles nodes w, w+8, ... (8 each)
    int w = t >> 6, lane = t & 63;
    int h2 = lane >> 4;    // head of channels 2*lane, 2*lane+1
    for (int nn = w; nn < 64; nn += 8) {
        int n = nodeBase + nn;
        if (n >= N) break;
        float ad = a_dst[n * 4 + h2];
        float p_self = __expf(lrelu(a_src[n * 4 + h2] + ad));
        unsigned us = ((const unsigned*)hb4)[(size_t)n * 64 + lane];
        float ax = acc[nn * 132 + 2 * lane]     + p_self * __uint_as_float(us << 16);
        float ay = acc[nn * 132 + 2 * lane + 1] + p_self * __uint_as_float(us & 0xFFFF0000u);
        float dsum = accd[nn * 4 + h2] + p_self;
        float inv = 1.0f / dsum;
        float2 b2 = ((const float2*)bias)[lane];
        float ox = ax * inv + b2.x;
        float oy = ay * inv + b2.y;
        ox = ox > 0.f ? ox : (__expf(ox) - 1.0f);
        oy = oy > 0.f ? oy : (__expf(oy) - 1.0f);
        ((float2*)out)[(size_t)n * 64 + lane] = float2{ox, oy};
    }
}

extern "C" void kernel_launch(void* const* d_in, const int* in_sizes, int n_in,
                              void* d_out, int out_size, void* d_ws, size_t ws_size,
                              hipStream_t stream) {
    const float* x = (const float*)d_in[0];
    const int* ei = (const int*)d_in[1];
    const float* W = (const float*)d_in[2];
    const float* att_src = (const float*)d_in[3];
    const float* att_dst = (const float*)d_in[4];
    const float* bias = (const float*)d_in[5];
    int N = in_sizes[0] / 128;
    int E = in_sizes[1] / 2;
    int NB2 = (N + 63) / 64;        // 1563 buckets of 64 nodes

    char* ws = (char*)d_ws;
    size_t o = 0;
    unsigned* hb = (unsigned*)(ws + o);   o += (size_t)N * 64 * 4;       // 25.6 MB
    float* a_src = (float*)(ws + o);      o += (size_t)N * 4 * 4;
    float* a_dst = (float*)(ws + o);      o += (size_t)N * 4 * 4;
    unsigned* ebuf = (unsigned*)(ws + o); o += (size_t)NB2 * BCAP * 4;   // 9.6 MB
    unsigned short* Wt = (unsigned short*)(ws + o); o += 128 * 128 * 2;
    unsigned* gcur = (unsigned*)(ws + o); o += (size_t)((NB2 + 1023) & ~1023) * 4;

    hipMemsetAsync(gcur, 0, (size_t)NB2 * 4, stream);

    k_wt<<<64, 256, 0, stream>>>(W, Wt);
    int EPB = 16384;
    int NBK = (E + EPB - 1) / EPB;  // 98 bucket blocks
    int nbG = (N + 127) / 128;      // 782 gemm blocks
    k_gembk<<<NBK + nbG, 512, 0, stream>>>(x, Wt, att_src, att_dst, hb, a_src, a_dst,
                                           ei, gcur, ebuf, N, E, NB2, NBK, EPB);
    k_bg<<<NB2, 512, 0, stream>>>((const uint4*)hb, ebuf, gcur, a_src, a_dst, bias,
                                  (float*)d_out, N);
}

// Round 21
// 147.471 us; speedup vs baseline: 8.6408x; 8.6408x over previous
//
#include <hip/hip_runtime.h>
#include <hip/hip_bf16.h>

#define NEG_SLOPE 0.2f
#define BCAP 5120u   // fixed ebuf region per 256-node bucket (mean 4093, +16 sigma)

typedef __attribute__((ext_vector_type(8))) short bf16x8;
typedef __attribute__((ext_vector_type(4))) float f32x4;

__device__ __forceinline__ float lrelu(float v) { return v > 0.0f ? v : NEG_SLOPE * v; }

__device__ __forceinline__ unsigned bf16pair(float a, float b) {
    unsigned ua = __float_as_uint(a), ub = __float_as_uint(b);
    ua = (ua + 0x7FFFu + ((ua >> 16) & 1u)) >> 16;
    ub = (ub + 0x7FFFu + ((ub >> 16) & 1u)) >> 16;
    return ua | (ub << 16);
}

__device__ __forceinline__ void gload16(const void* g, void* l) {
    __builtin_amdgcn_global_load_lds(
        (const __attribute__((address_space(1))) unsigned*)g,
        (__attribute__((address_space(3))) unsigned*)l, 16, 0, 0);
}

// ---------------- Wt: W fp32 [k][n] -> Wt bf16 [n][k] ----------------
__global__ __launch_bounds__(256) void k_wt(const float* __restrict__ W,
                                            unsigned short* __restrict__ Wt) {
    int gid = blockIdx.x * 256 + threadIdx.x;
    int col = gid >> 7, k = gid & 127;
    float v = W[(size_t)k * 128 + col];
    unsigned u = __float_as_uint(v);
    u = (u + 0x7FFFu + ((u >> 16) & 1u)) >> 16;
    Wt[col * 128 + k] = (unsigned short)u;
}

// ---------------- fused: bucket blocks (first NBK) + gemm blocks ------------
__global__ __launch_bounds__(512) void k_gembk(const float* __restrict__ x,
                                               const unsigned short* __restrict__ Wt,
                                               const float* __restrict__ att_src,
                                               const float* __restrict__ att_dst,
                                               unsigned* __restrict__ hb,
                                               float* __restrict__ a_src,
                                               float* __restrict__ a_dst,
                                               const int* __restrict__ ei,
                                               unsigned* __restrict__ gcur,
                                               unsigned* __restrict__ ebuf,
                                               int N, int E, int NB, int NBK, int EPB) {
    __shared__ unsigned char sm[65536];
    int t = threadIdx.x;

    if ((int)blockIdx.x < NBK) {
        // ---- bucket path: fixed regions b*BCAP, 4B entries src|(d&255)<<24 --
        unsigned* cnt = (unsigned*)sm;
        unsigned* cur2 = (unsigned*)(sm + 2048);
        unsigned* lbase = (unsigned*)(sm + 4096);
        int base = blockIdx.x * EPB;
        int lim = base + EPB;
        if (lim > E) lim = E;
        for (int j = t; j < NB; j += 512) { cnt[j] = 0u; cur2[j] = 0u; }
        __syncthreads();
        for (int i = base + t; i < lim; i += 512)
            atomicAdd(&cnt[(unsigned)ei[(size_t)E + i] >> 8], 1u);
        __syncthreads();
        for (int j = t; j < NB; j += 512) {
            unsigned c = cnt[j];
            lbase[j] = c ? ((unsigned)j * BCAP + atomicAdd(&gcur[j], c)) : 0u;
        }
        __syncthreads();
        for (int i = base + t; i < lim; i += 512) {
            unsigned s = (unsigned)ei[i];
            unsigned d = (unsigned)ei[(size_t)E + i];
            unsigned b = d >> 8;
            unsigned k = atomicAdd(&cur2[b], 1u);
            unsigned slot = lbase[b] + k;
            if (slot < (b + 1u) * BCAP) ebuf[slot] = s | ((d & 255u) << 24);
        }
        return;
    }

    // ---------------- gemm path ----------------
    unsigned char* smA = sm;
    unsigned char* smB = sm + 32768;
    int w = t >> 6, lane = t & 63;
    int row0 = ((int)blockIdx.x - NBK) * 128;

#pragma unroll
    for (int it = 0; it < 4; ++it) {
        int L = it * 512 + t;
        int r = L >> 4, c = L & 15;
        int gr = row0 + r;
        if (gr >= N) gr = N - 1;
        float4 f0 = ((const float4*)x)[(size_t)gr * 32 + c * 2];
        float4 f1 = ((const float4*)x)[(size_t)gr * 32 + c * 2 + 1];
        uint4 u;
        u.x = bf16pair(f0.x, f0.y);
        u.y = bf16pair(f0.z, f0.w);
        u.z = bf16pair(f1.x, f1.y);
        u.w = bf16pair(f1.z, f1.w);
        *(uint4*)&smA[r * 256 + ((c ^ (r & 7)) * 16)] = u;
    }
#pragma unroll
    for (int it = 0; it < 4; ++it) {
        int L = w * 256 + it * 64 + lane;
        int r = L >> 4, c = L & 15;
        int cg = c ^ (r & 7);
        gload16((const unsigned*)Wt + r * 64 + cg * 4, smB + (size_t)w * 4096 + it * 1024);
    }
    __syncthreads();

    int lr = lane & 15, lg = lane >> 4;
    int ar = w * 16 + lr;

    f32x4 acc[8];
#pragma unroll
    for (int j = 0; j < 8; ++j)
#pragma unroll
        for (int q = 0; q < 4; ++q) acc[j][q] = 0.f;

#pragma unroll
    for (int kc = 0; kc < 4; ++kc) {
        bf16x8 av = *(const bf16x8*)&smA[ar * 256 + (((kc * 4 + lg) ^ (ar & 7)) * 16)];
        bf16x8 bv[8];
#pragma unroll
        for (int cf = 0; cf < 8; ++cf) {
            int bc = cf * 16 + lr;
            bv[cf] = *(const bf16x8*)&smB[bc * 256 + (((kc * 4 + lg) ^ (bc & 7)) * 16)];
        }
#pragma unroll
        for (int cf = 0; cf < 8; ++cf)
            acc[cf] = __builtin_amdgcn_mfma_f32_16x16x32_bf16(av, bv[cf], acc[cf], 0, 0, 0);
    }

    float att_s[8], att_d[8];
#pragma unroll
    for (int cf = 0; cf < 8; ++cf) {
        att_s[cf] = att_src[cf * 16 + lr];
        att_d[cf] = att_dst[cf * 16 + lr];
    }
#pragma unroll
    for (int reg = 0; reg < 4; ++reg) {
        int row = row0 + w * 16 + lg * 4 + reg;
        float ps[4], pd[4];
#pragma unroll
        for (int hh = 0; hh < 4; ++hh) {
            ps[hh] = acc[2 * hh][reg] * att_s[2 * hh] + acc[2 * hh + 1][reg] * att_s[2 * hh + 1];
            pd[hh] = acc[2 * hh][reg] * att_d[2 * hh] + acc[2 * hh + 1][reg] * att_d[2 * hh + 1];
        }
#pragma unroll
        for (int m = 1; m <= 8; m <<= 1) {
#pragma unroll
            for (int hh = 0; hh < 4; ++hh) {
                ps[hh] += __shfl_xor(ps[hh], m);
                pd[hh] += __shfl_xor(pd[hh], m);
            }
        }
        if (lr == 0 && row < N) {
            ((float4*)a_src)[row] = float4{ps[0], ps[1], ps[2], ps[3]};
            ((float4*)a_dst)[row] = float4{pd[0], pd[1], pd[2], pd[3]};
        }
    }

    unsigned char* scratch = smA + (size_t)w * 4096;
#pragma unroll
    for (int cf = 0; cf < 8; ++cf) {
#pragma unroll
        for (int reg = 0; reg < 4; ++reg) {
            float v = acc[cf][reg];
            float vo = __shfl_xor(v, 1);
            if (!(lane & 1))
                *(unsigned*)&scratch[(lg * 4 + reg) * 256 + cf * 32 + (lr >> 1) * 4] =
                    bf16pair(v, vo);
        }
    }
#pragma unroll
    for (int q = 0; q < 4; ++q) {
        uint4 u = *(const uint4*)&scratch[q * 1024 + lane * 16];
        int row = row0 + w * 16 + q * 4 + lg;
        if (row < N) ((uint4*)hb)[(size_t)row * 16 + lr] = u;
    }
}

// ---- scanB: single block, exclusive scan of bucket totals -> blockScan ------
__global__ __launch_bounds__(512) void k_scanB(const unsigned* __restrict__ gcur,
                                               unsigned* __restrict__ blockScan, int NB) {
    __shared__ unsigned s[512];
    int t = threadIdx.x;
    unsigned v = (t < NB) ? min(gcur[t], BCAP) : 0u;
    s[t] = v;
    __syncthreads();
    for (int off = 1; off < 512; off <<= 1) {
        unsigned a = (t >= off) ? s[t - off] : 0u;
        __syncthreads();
        s[t] += a;
        __syncthreads();
    }
    if (t < NB) blockScan[t] = s[t] - v;
}

// ---- place: derive per-node deg/part from bucket run, permute to CSR --------
__global__ __launch_bounds__(256) void k_place(const unsigned* __restrict__ ebuf,
                                               const unsigned* __restrict__ gcur,
                                               const unsigned* __restrict__ blockScan,
                                               unsigned* __restrict__ deg,
                                               unsigned* __restrict__ part,
                                               unsigned* __restrict__ csr_src) {
    __shared__ unsigned cnt[256];
    __shared__ unsigned sc[256];
    __shared__ unsigned excl[256];
    __shared__ unsigned curL[256];
    int t = threadIdx.x;
    int b = blockIdx.x;
    cnt[t] = 0u;
    curL[t] = 0u;
    __syncthreads();
    unsigned total = min(gcur[b], BCAP);
    unsigned rbase = (unsigned)b * BCAP;
    for (unsigned i = t; i < total; i += 256)
        atomicAdd(&cnt[ebuf[rbase + i] >> 24], 1u);
    __syncthreads();
    unsigned v = cnt[t];
    sc[t] = v;
    __syncthreads();
    for (int off = 1; off < 256; off <<= 1) {
        unsigned a = (t >= off) ? sc[t - off] : 0u;
        __syncthreads();
        sc[t] += a;
        __syncthreads();
    }
    excl[t] = sc[t] - v;
    deg[b * 256 + t] = v;
    part[b * 256 + t] = sc[t] - v;
    __syncthreads();
    unsigned wbase = blockScan[b];
    for (unsigned i = t; i < total; i += 256) {
        unsigned e = ebuf[rbase + i];
        unsigned dLow = e >> 24;
        unsigned r = atomicAdd(&curL[dLow], 1u);
        csr_src[wbase + excl[dLow] + r] = e & 0x00FFFFFFu;
    }
}

// --- gather: 1 wave/node; 8-edge batches, 4 edge-groups x 16 lanes (R16) -----
__global__ __launch_bounds__(256) void k_gather(const uint4* __restrict__ hb4,
                                                const unsigned* __restrict__ csr_src,
                                                const unsigned* __restrict__ part,
                                                const unsigned* __restrict__ blockScan,
                                                const unsigned* __restrict__ deg,
                                                const float* __restrict__ a_src,
                                                const float* __restrict__ a_dst,
                                                const float* __restrict__ bias,
                                                float* __restrict__ out, int N) {
    int n = (int)((blockIdx.x * 256 + threadIdx.x) >> 6);
    int lane = threadIdx.x & 63;
    if (n >= N) return;
    int g = lane >> 4;        // edge group
    int L = lane & 15;        // channel block: channels 8L..8L+7
    int head = L >> 2;
    unsigned off = part[n] + blockScan[n >> 8];
    unsigned end = off + deg[n];
    float ad_n = a_dst[n * 4 + head];
    float acc[8];
#pragma unroll
    for (int i = 0; i < 8; ++i) acc[i] = 0.f;
    float dsum = 0.f;
    for (unsigned b = off; b < end; b += 8) {
        unsigned sidx = csr_src[min(b + (unsigned)(lane & 7), end - 1)];
#pragma unroll
        for (int sub = 0; sub < 2; ++sub) {
            int eidx = sub * 4 + g;
            unsigned s = (unsigned)__shfl((int)sidx, eidx);
            float as = a_src[s * 4 + head];
            uint4 u = hb4[s * 16u + (unsigned)L];
            float p = __expf(lrelu(as + ad_n));
            p = (b + (unsigned)eidx < end) ? p : 0.f;
            acc[0] = fmaf(p, __uint_as_float(u.x << 16), acc[0]);
            acc[1] = fmaf(p, __uint_as_float(u.x & 0xFFFF0000u), acc[1]);
            acc[2] = fmaf(p, __uint_as_float(u.y << 16), acc[2]);
            acc[3] = fmaf(p, __uint_as_float(u.y & 0xFFFF0000u), acc[3]);
            acc[4] = fmaf(p, __uint_as_float(u.z << 16), acc[4]);
            acc[5] = fmaf(p, __uint_as_float(u.z & 0xFFFF0000u), acc[5]);
            acc[6] = fmaf(p, __uint_as_float(u.w << 16), acc[6]);
            acc[7] = fmaf(p, __uint_as_float(u.w & 0xFFFF0000u), acc[7]);
            dsum += p;
        }
    }
    // cross-group reduction
#pragma unroll
    for (int m = 16; m <= 32; m <<= 1) {
#pragma unroll
        for (int i = 0; i < 8; ++i) acc[i] += __shfl_xor(acc[i], m);
        dsum += __shfl_xor(dsum, m);
    }
    // self loop
    float p_self = __expf(lrelu(a_src[n * 4 + head] + ad_n));
    uint4 us = hb4[(unsigned)n * 16u + (unsigned)L];
    acc[0] = fmaf(p_self, __uint_as_float(us.x << 16), acc[0]);
    acc[1] = fmaf(p_self, __uint_as_float(us.x & 0xFFFF0000u), acc[1]);
    acc[2] = fmaf(p_self, __uint_as_float(us.y << 16), acc[2]);
    acc[3] = fmaf(p_self, __uint_as_float(us.y & 0xFFFF0000u), acc[3]);
    acc[4] = fmaf(p_self, __uint_as_float(us.z << 16), acc[4]);
    acc[5] = fmaf(p_self, __uint_as_float(us.z & 0xFFFF0000u), acc[5]);
    acc[6] = fmaf(p_self, __uint_as_float(us.w << 16), acc[6]);
    acc[7] = fmaf(p_self, __uint_as_float(us.w & 0xFFFF0000u), acc[7]);
    dsum += p_self;
    float inv = 1.0f / dsum;
    if (g == 0) {
        float4 b0 = ((const float4*)bias)[L * 2];
        float4 b1 = ((const float4*)bias)[L * 2 + 1];
        float4 o0, o1;
        o0.x = acc[0] * inv + b0.x;
        o0.y = acc[1] * inv + b0.y;
        o0.z = acc[2] * inv + b0.z;
        o0.w = acc[3] * inv + b0.w;
        o1.x = acc[4] * inv + b1.x;
        o1.y = acc[5] * inv + b1.y;
        o1.z = acc[6] * inv + b1.z;
        o1.w = acc[7] * inv + b1.w;
        o0.x = o0.x > 0.f ? o0.x : (__expf(o0.x) - 1.0f);
        o0.y = o0.y > 0.f ? o0.y : (__expf(o0.y) - 1.0f);
        o0.z = o0.z > 0.f ? o0.z : (__expf(o0.z) - 1.0f);
        o0.w = o0.w > 0.f ? o0.w : (__expf(o0.w) - 1.0f);
        o1.x = o1.x > 0.f ? o1.x : (__expf(o1.x) - 1.0f);
        o1.y = o1.y > 0.f ? o1.y : (__expf(o1.y) - 1.0f);
        o1.z = o1.z > 0.f ? o1.z : (__expf(o1.z) - 1.0f);
        o1.w = o1.w > 0.f ? o1.w : (__expf(o1.w) - 1.0f);
        ((float4*)out)[(size_t)n * 32 + L * 2] = o0;
        ((float4*)out)[(size_t)n * 32 + L * 2 + 1] = o1;
    }
}

extern "C" void kernel_launch(void* const* d_in, const int* in_sizes, int n_in,
                              void* d_out, int out_size, void* d_ws, size_t ws_size,
                              hipStream_t stream) {
    const float* x = (const float*)d_in[0];
    const int* ei = (const int*)d_in[1];
    const float* W = (const float*)d_in[2];
    const float* att_src = (const float*)d_in[3];
    const float* att_dst = (const float*)d_in[4];
    const float* bias = (const float*)d_in[5];
    int N = in_sizes[0] / 128;
    int E = in_sizes[1] / 2;
    int NB = (N + 255) / 256;       // 391 buckets of 256 nodes

    char* ws = (char*)d_ws;
    size_t o = 0;
    unsigned* hb = (unsigned*)(ws + o);   o += (size_t)N * 64 * 4;     // 25.6 MB
    float* a_src = (float*)(ws + o);      o += (size_t)N * 4 * 4;
    float* a_dst = (float*)(ws + o);      o += (size_t)N * 4 * 4;
    unsigned* csr_src = (unsigned*)(ws + o); o += (size_t)E * 4;       // 6.4 MB
    unsigned* ebuf = (unsigned*)(ws + o); o += (size_t)NB * BCAP * 4;  // 8.0 MB
    unsigned short* Wt = (unsigned short*)(ws + o); o += 128 * 128 * 2;
    unsigned* deg = (unsigned*)(ws + o);  o += (size_t)NB * 256 * 4;
    unsigned* part = (unsigned*)(ws + o); o += (size_t)NB * 256 * 4;
    unsigned* gcur = (unsigned*)(ws + o); o += 2048;
    unsigned* blockScan = (unsigned*)(ws + o); o += 2048;

    hipMemsetAsync(gcur, 0, 2048, stream);

    k_wt<<<64, 256, 0, stream>>>(W, Wt);
    int EPB = 16384;
    int NBK = (E + EPB - 1) / EPB;  // 98 bucket blocks
    int nbG = (N + 127) / 128;      // 782 gemm blocks
    k_gembk<<<NBK + nbG, 512, 0, stream>>>(x, Wt, att_src, att_dst, hb, a_src, a_dst,
                                           ei, gcur, ebuf, N, E, NB, NBK, EPB);
    k_scanB<<<1, 512, 0, stream>>>(gcur, blockScan, NB);
    k_place<<<NB, 256, 0, stream>>>(ebuf, gcur, blockScan, deg, part, csr_src);
    k_gather<<<(N * 64 + 255) / 256, 256, 0, stream>>>((const uint4*)hb, csr_src, part,
                                                       blockScan, deg, a_src, a_dst, bias,
                                                       (float*)d_out, N);
}

// Round 22
// 139.801 us; speedup vs baseline: 9.1149x; 1.0549x over previous
//
#include <hip/hip_runtime.h>
#include <hip/hip_bf16.h>

#define NEG_SLOPE 0.2f
#define BCAP 5120u   // fixed ebuf/csr region per 256-node bucket (mean 4093, +16 sigma)

typedef __attribute__((ext_vector_type(8))) short bf16x8;
typedef __attribute__((ext_vector_type(4))) float f32x4;

__device__ __forceinline__ float lrelu(float v) { return v > 0.0f ? v : NEG_SLOPE * v; }

__device__ __forceinline__ unsigned bf16pair(float a, float b) {
    unsigned ua = __float_as_uint(a), ub = __float_as_uint(b);
    ua = (ua + 0x7FFFu + ((ua >> 16) & 1u)) >> 16;
    ub = (ub + 0x7FFFu + ((ub >> 16) & 1u)) >> 16;
    return ua | (ub << 16);
}

__device__ __forceinline__ void gload16(const void* g, void* l) {
    __builtin_amdgcn_global_load_lds(
        (const __attribute__((address_space(1))) unsigned*)g,
        (__attribute__((address_space(3))) unsigned*)l, 16, 0, 0);
}

// ------- Wt: W fp32 [k][n] -> Wt bf16 [n][k]; block 0 zeroes gcur -----------
__global__ __launch_bounds__(256) void k_wt(const float* __restrict__ W,
                                            unsigned short* __restrict__ Wt,
                                            unsigned* __restrict__ gcur) {
    int t = threadIdx.x;
    if (blockIdx.x == 0) {
        gcur[t] = 0u;
        gcur[t + 256] = 0u;
    }
    int gid = blockIdx.x * 256 + t;
    int col = gid >> 7, k = gid & 127;
    float v = W[(size_t)k * 128 + col];
    unsigned u = __float_as_uint(v);
    u = (u + 0x7FFFu + ((u >> 16) & 1u)) >> 16;
    Wt[col * 128 + k] = (unsigned short)u;
}

// ---------------- fused: bucket blocks (first NBK) + gemm blocks ------------
__global__ __launch_bounds__(512) void k_gembk(const float* __restrict__ x,
                                               const unsigned short* __restrict__ Wt,
                                               const float* __restrict__ att_src,
                                               const float* __restrict__ att_dst,
                                               unsigned* __restrict__ hb,
                                               float* __restrict__ a_src,
                                               float* __restrict__ a_dst,
                                               const int* __restrict__ ei,
                                               unsigned* __restrict__ gcur,
                                               unsigned* __restrict__ ebuf,
                                               int N, int E, int NB, int NBK, int EPB) {
    __shared__ unsigned char sm[65536];
    int t = threadIdx.x;

    if ((int)blockIdx.x < NBK) {
        // ---- bucket path: fixed regions b*BCAP; dst staged in LDS ----
        unsigned* dstbuf = (unsigned*)sm;              // [8192] 32 KB
        unsigned* cnt = (unsigned*)(sm + 32768);       // [512]
        unsigned* cur2 = (unsigned*)(sm + 34816);      // [512]
        unsigned* lbase = (unsigned*)(sm + 36864);     // [512]
        int base = blockIdx.x * EPB;
        int lim = base + EPB;
        if (lim > E) lim = E;
        int n_sl = lim - base;
        for (int j = t; j < NB; j += 512) { cnt[j] = 0u; cur2[j] = 0u; }
        __syncthreads();
        for (int i = t; i < n_sl; i += 512) {
            unsigned d = (unsigned)ei[(size_t)E + base + i];
            dstbuf[i] = d;
            atomicAdd(&cnt[d >> 8], 1u);
        }
        __syncthreads();
        for (int j = t; j < NB; j += 512) {
            unsigned c = cnt[j];
            lbase[j] = c ? ((unsigned)j * BCAP + atomicAdd(&gcur[j], c)) : 0u;
        }
        __syncthreads();
        for (int i = t; i < n_sl; i += 512) {
            unsigned s = (unsigned)ei[base + i];
            unsigned d = dstbuf[i];
            unsigned b = d >> 8;
            unsigned k = atomicAdd(&cur2[b], 1u);
            unsigned slot = lbase[b] + k;
            if (slot < (b + 1u) * BCAP) ebuf[slot] = s | ((d & 255u) << 24);
        }
        return;
    }

    // ---------------- gemm path ----------------
    unsigned char* smA = sm;
    unsigned char* smB = sm + 32768;
    int w = t >> 6, lane = t & 63;
    int row0 = ((int)blockIdx.x - NBK) * 128;

#pragma unroll
    for (int it = 0; it < 4; ++it) {
        int L = it * 512 + t;
        int r = L >> 4, c = L & 15;
        int gr = row0 + r;
        if (gr >= N) gr = N - 1;
        float4 f0 = ((const float4*)x)[(size_t)gr * 32 + c * 2];
        float4 f1 = ((const float4*)x)[(size_t)gr * 32 + c * 2 + 1];
        uint4 u;
        u.x = bf16pair(f0.x, f0.y);
        u.y = bf16pair(f0.z, f0.w);
        u.z = bf16pair(f1.x, f1.y);
        u.w = bf16pair(f1.z, f1.w);
        *(uint4*)&smA[r * 256 + ((c ^ (r & 7)) * 16)] = u;
    }
#pragma unroll
    for (int it = 0; it < 4; ++it) {
        int L = w * 256 + it * 64 + lane;
        int r = L >> 4, c = L & 15;
        int cg = c ^ (r & 7);
        gload16((const unsigned*)Wt + r * 64 + cg * 4, smB + (size_t)w * 4096 + it * 1024);
    }
    __syncthreads();

    int lr = lane & 15, lg = lane >> 4;
    int ar = w * 16 + lr;

    f32x4 acc[8];
#pragma unroll
    for (int j = 0; j < 8; ++j)
#pragma unroll
        for (int q = 0; q < 4; ++q) acc[j][q] = 0.f;

#pragma unroll
    for (int kc = 0; kc < 4; ++kc) {
        bf16x8 av = *(const bf16x8*)&smA[ar * 256 + (((kc * 4 + lg) ^ (ar & 7)) * 16)];
        bf16x8 bv[8];
#pragma unroll
        for (int cf = 0; cf < 8; ++cf) {
            int bc = cf * 16 + lr;
            bv[cf] = *(const bf16x8*)&smB[bc * 256 + (((kc * 4 + lg) ^ (bc & 7)) * 16)];
        }
#pragma unroll
        for (int cf = 0; cf < 8; ++cf)
            acc[cf] = __builtin_amdgcn_mfma_f32_16x16x32_bf16(av, bv[cf], acc[cf], 0, 0, 0);
    }

    float att_s[8], att_d[8];
#pragma unroll
    for (int cf = 0; cf < 8; ++cf) {
        att_s[cf] = att_src[cf * 16 + lr];
        att_d[cf] = att_dst[cf * 16 + lr];
    }
#pragma unroll
    for (int reg = 0; reg < 4; ++reg) {
        int row = row0 + w * 16 + lg * 4 + reg;
        float ps[4], pd[4];
#pragma unroll
        for (int hh = 0; hh < 4; ++hh) {
            ps[hh] = acc[2 * hh][reg] * att_s[2 * hh] + acc[2 * hh + 1][reg] * att_s[2 * hh + 1];
            pd[hh] = acc[2 * hh][reg] * att_d[2 * hh] + acc[2 * hh + 1][reg] * att_d[2 * hh + 1];
        }
#pragma unroll
        for (int m = 1; m <= 8; m <<= 1) {
#pragma unroll
            for (int hh = 0; hh < 4; ++hh) {
                ps[hh] += __shfl_xor(ps[hh], m);
                pd[hh] += __shfl_xor(pd[hh], m);
            }
        }
        if (lr == 0 && row < N) {
            ((float4*)a_src)[row] = float4{ps[0], ps[1], ps[2], ps[3]};
            ((float4*)a_dst)[row] = float4{pd[0], pd[1], pd[2], pd[3]};
        }
    }

    unsigned char* scratch = smA + (size_t)w * 4096;
#pragma unroll
    for (int cf = 0; cf < 8; ++cf) {
#pragma unroll
        for (int reg = 0; reg < 4; ++reg) {
            float v = acc[cf][reg];
            float vo = __shfl_xor(v, 1);
            if (!(lane & 1))
                *(unsigned*)&scratch[(lg * 4 + reg) * 256 + cf * 32 + (lr >> 1) * 4] =
                    bf16pair(v, vo);
        }
    }
#pragma unroll
    for (int q = 0; q < 4; ++q) {
        uint4 u = *(const uint4*)&scratch[q * 1024 + lane * 16];
        int row = row0 + w * 16 + q * 4 + lg;
        if (row < N) ((uint4*)hb)[(size_t)row * 16 + lr] = u;
    }
}

// ---- place: derive per-node deg/part, permute into fixed csr region --------
__global__ __launch_bounds__(256) void k_place(const unsigned* __restrict__ ebuf,
                                               const unsigned* __restrict__ gcur,
                                               unsigned* __restrict__ deg,
                                               unsigned* __restrict__ part,
                                               unsigned* __restrict__ csr_src) {
    __shared__ unsigned cnt[256];
    __shared__ unsigned sc[256];
    __shared__ unsigned excl[256];
    __shared__ unsigned curL[256];
    int t = threadIdx.x;
    int b = blockIdx.x;
    cnt[t] = 0u;
    curL[t] = 0u;
    __syncthreads();
    unsigned total = min(gcur[b], BCAP);
    unsigned rbase = (unsigned)b * BCAP;
    for (unsigned i = t; i < total; i += 256)
        atomicAdd(&cnt[ebuf[rbase + i] >> 24], 1u);
    __syncthreads();
    unsigned v = cnt[t];
    sc[t] = v;
    __syncthreads();
    for (int off = 1; off < 256; off <<= 1) {
        unsigned a = (t >= off) ? sc[t - off] : 0u;
        __syncthreads();
        sc[t] += a;
        __syncthreads();
    }
    excl[t] = sc[t] - v;
    deg[b * 256 + t] = v;
    part[b * 256 + t] = sc[t] - v;
    __syncthreads();
    for (unsigned i = t; i < total; i += 256) {
        unsigned e = ebuf[rbase + i];
        unsigned dLow = e >> 24;
        unsigned r = atomicAdd(&curL[dLow], 1u);
        csr_src[rbase + excl[dLow] + r] = e & 0x00FFFFFFu;
    }
}

// --- gather: 1 wave/node; 8-edge batches, 4 edge-groups x 16 lanes ----------
__global__ __launch_bounds__(256) void k_gather(const uint4* __restrict__ hb4,
                                                const unsigned* __restrict__ csr_src,
                                                const unsigned* __restrict__ part,
                                                const unsigned* __restrict__ deg,
                                                const float* __restrict__ a_src,
                                                const float* __restrict__ a_dst,
                                                const float* __restrict__ bias,
                                                float* __restrict__ out, int N) {
    int n = (int)((blockIdx.x * 256 + threadIdx.x) >> 6);
    int lane = threadIdx.x & 63;
    if (n >= N) return;
    int g = lane >> 4;        // edge group
    int L = lane & 15;        // channel block: channels 8L..8L+7
    int head = L >> 2;
    unsigned off = (unsigned)(n >> 8) * BCAP + part[n];
    unsigned end = off + deg[n];
    float ad_n = a_dst[n * 4 + head];
    float acc[8];
#pragma unroll
    for (int i = 0; i < 8; ++i) acc[i] = 0.f;
    float dsum = 0.f;
    for (unsigned b = off; b < end; b += 8) {
        unsigned sidx = csr_src[min(b + (unsigned)(lane & 7), end - 1)];
#pragma unroll
        for (int sub = 0; sub < 2; ++sub) {
            int eidx = sub * 4 + g;
            unsigned s = (unsigned)__shfl((int)sidx, eidx);
            float as = a_src[s * 4 + head];
            uint4 u = hb4[s * 16u + (unsigned)L];
            float p = __expf(lrelu(as + ad_n));
            p = (b + (unsigned)eidx < end) ? p : 0.f;
            acc[0] = fmaf(p, __uint_as_float(u.x << 16), acc[0]);
            acc[1] = fmaf(p, __uint_as_float(u.x & 0xFFFF0000u), acc[1]);
            acc[2] = fmaf(p, __uint_as_float(u.y << 16), acc[2]);
            acc[3] = fmaf(p, __uint_as_float(u.y & 0xFFFF0000u), acc[3]);
            acc[4] = fmaf(p, __uint_as_float(u.z << 16), acc[4]);
            acc[5] = fmaf(p, __uint_as_float(u.z & 0xFFFF0000u), acc[5]);
            acc[6] = fmaf(p, __uint_as_float(u.w << 16), acc[6]);
            acc[7] = fmaf(p, __uint_as_float(u.w & 0xFFFF0000u), acc[7]);
            dsum += p;
        }
    }
    // cross-group reduction
#pragma unroll
    for (int m = 16; m <= 32; m <<= 1) {
#pragma unroll
        for (int i = 0; i < 8; ++i) acc[i] += __shfl_xor(acc[i], m);
        dsum += __shfl_xor(dsum, m);
    }
    // self loop
    float p_self = __expf(lrelu(a_src[n * 4 + head] + ad_n));
    uint4 us = hb4[(unsigned)n * 16u + (unsigned)L];
    acc[0] = fmaf(p_self, __uint_as_float(us.x << 16), acc[0]);
    acc[1] = fmaf(p_self, __uint_as_float(us.x & 0xFFFF0000u), acc[1]);
    acc[2] = fmaf(p_self, __uint_as_float(us.y << 16), acc[2]);
    acc[3] = fmaf(p_self, __uint_as_float(us.y & 0xFFFF0000u), acc[3]);
    acc[4] = fmaf(p_self, __uint_as_float(us.z << 16), acc[4]);
    acc[5] = fmaf(p_self, __uint_as_float(us.z & 0xFFFF0000u), acc[5]);
    acc[6] = fmaf(p_self, __uint_as_float(us.w << 16), acc[6]);
    acc[7] = fmaf(p_self, __uint_as_float(us.w & 0xFFFF0000u), acc[7]);
    dsum += p_self;
    float inv = 1.0f / dsum;
    if (g == 0) {
        float4 b0 = ((const float4*)bias)[L * 2];
        float4 b1 = ((const float4*)bias)[L * 2 + 1];
        float4 o0, o1;
        o0.x = acc[0] * inv + b0.x;
        o0.y = acc[1] * inv + b0.y;
        o0.z = acc[2] * inv + b0.z;
        o0.w = acc[3] * inv + b0.w;
        o1.x = acc[4] * inv + b1.x;
        o1.y = acc[5] * inv + b1.y;
        o1.z = acc[6] * inv + b1.z;
        o1.w = acc[7] * inv + b1.w;
        o0.x = o0.x > 0.f ? o0.x : (__expf(o0.x) - 1.0f);
        o0.y = o0.y > 0.f ? o0.y : (__expf(o0.y) - 1.0f);
        o0.z = o0.z > 0.f ? o0.z : (__expf(o0.z) - 1.0f);
        o0.w = o0.w > 0.f ? o0.w : (__expf(o0.w) - 1.0f);
        o1.x = o1.x > 0.f ? o1.x : (__expf(o1.x) - 1.0f);
        o1.y = o1.y > 0.f ? o1.y : (__expf(o1.y) - 1.0f);
        o1.z = o1.z > 0.f ? o1.z : (__expf(o1.z) - 1.0f);
        o1.w = o1.w > 0.f ? o1.w : (__expf(o1.w) - 1.0f);
        ((float4*)out)[(size_t)n * 32 + L * 2] = o0;
        ((float4*)out)[(size_t)n * 32 + L * 2 + 1] = o1;
    }
}

extern "C" void kernel_launch(void* const* d_in, const int* in_sizes, int n_in,
                              void* d_out, int out_size, void* d_ws, size_t ws_size,
                              hipStream_t stream) {
    const float* x = (const float*)d_in[0];
    const int* ei = (const int*)d_in[1];
    const float* W = (const float*)d_in[2];
    const float* att_src = (const float*)d_in[3];
    const float* att_dst = (const float*)d_in[4];
    const float* bias = (const float*)d_in[5];
    int N = in_sizes[0] / 128;
    int E = in_sizes[1] / 2;
    int NB = (N + 255) / 256;       // 391 buckets of 256 nodes

    char* ws = (char*)d_ws;
    size_t o = 0;
    unsigned* hb = (unsigned*)(ws + o);   o += (size_t)N * 64 * 4;      // 25.6 MB
    float* a_src = (float*)(ws + o);      o += (size_t)N * 4 * 4;
    float* a_dst = (float*)(ws + o);      o += (size_t)N * 4 * 4;
    unsigned* csr_src = (unsigned*)(ws + o); o += (size_t)NB * BCAP * 4; // 8.0 MB
    unsigned* ebuf = (unsigned*)(ws + o); o += (size_t)NB * BCAP * 4;    // 8.0 MB
    unsigned short* Wt = (unsigned short*)(ws + o); o += 128 * 128 * 2;
    unsigned* deg = (unsigned*)(ws + o);  o += (size_t)NB * 256 * 4;
    unsigned* part = (unsigned*)(ws + o); o += (size_t)NB * 256 * 4;
    unsigned* gcur = (unsigned*)(ws + o); o += 2048;

    k_wt<<<64, 256, 0, stream>>>(W, Wt, gcur);
    int EPB = 8192;
    int NBK = (E + EPB - 1) / EPB;  // 196 bucket blocks
    int nbG = (N + 127) / 128;      // 782 gemm blocks
    k_gembk<<<NBK + nbG, 512, 0, stream>>>(x, Wt, att_src, att_dst, hb, a_src, a_dst,
                                           ei, gcur, ebuf, N, E, NB, NBK, EPB);
    k_place<<<NB, 256, 0, stream>>>(ebuf, gcur, deg, part, csr_src);
    k_gather<<<(N * 64 + 255) / 256, 256, 0, stream>>>((const uint4*)hb, csr_src, part,
                                                       deg, a_src, a_dst, bias,
                                                       (float*)d_out, N);
}